// Round 1
// 427.248 us; speedup vs baseline: 1.1001x; 1.1001x over previous
//
#include <hip/hip_runtime.h>
#include <hip/hip_bf16.h>
#include <stdint.h>

// out = x @ (sum_e w1[e] @ w2[e])   -- reassociated two-einsum.
// GEMM1 (new): 256x256-tile 8-phase schedule (T2+T3+T4+T5), atomic split-K over
//   z = expert * zdiv + kchunk.  A=w2t, Bt=w1b (both bf16 [e][row][k], ld=4096).
// GEMM2: old 2-barrier 64x128 kernel (small, revisit later).

#define BN 128

typedef __attribute__((ext_vector_type(8))) short short8;
typedef __attribute__((ext_vector_type(4))) float float4v;
typedef __attribute__((ext_vector_type(4))) unsigned int uint4v;

__device__ __forceinline__ unsigned int rne_hi(unsigned int u) {
  return u + 0x7fffu + ((u >> 16) & 1u);
}

__device__ __forceinline__ unsigned int pack_bf16(float lo, float hi) {
  unsigned int ulo = rne_hi(__float_as_uint(lo));
  unsigned int uhi = rne_hi(__float_as_uint(hi));
  return __builtin_amdgcn_perm(uhi, ulo, 0x07060302u);
}

__device__ __forceinline__ void load_lds_16B(const void* g, void* lds) {
  __builtin_amdgcn_global_load_lds(
      (__attribute__((address_space(1))) void*)(uintptr_t)g,
      (__attribute__((address_space(3))) void*)(unsigned int)(uintptr_t)lds,
      16, 0, 0);
}

// ---------------------------------------------------------------------------
// GEMM1: C[1024][1024] fp32 (atomic +=) = A[e] * Bt[e]^T over z-chunks.
// 8 waves (2M x 4N), per-wave 128x64 output, BK=64, 2 K-tiles per 8-phase iter.
// LDS per operand: [buf2][half2][128 rows][64 k] bf16 (64 KiB) -> 128 KiB total.
// XOR swizzle: logical 16B-granule cg of row r stored at phys cg ^ (r&7)
//   (read: 16-lane groups hit 8 distinct granules -> 2-way max = free).
// Staging: global_load_lds w=16; LDS dest linear, SOURCE pre-swizzled:
//   lane ln fetches logical cg = (ln&7) ^ ((ln>>3)&7), row = base + (ln>>3).
// Phase schedule per K-tile n in buffer b (other buffer ob):
//   q1: ds A(M0)x8 + B(N0)x4 ; stage ob.A0 (tile n+1) ; bar; lgkm0; MFMA M0N0; bar
//   q2: ds B(N1)x4           ; stage ob.A1 (tile n+1) ; bar; lgkm0; MFMA M0N1; bar
//   q3: ds A(M1)x8           ; stage b.B0  (tile n+2) ; bar; lgkm0; MFMA M1N1; bar
//   q4:                        stage b.B1  (tile n+2) ; bar;        MFMA M1N0;
//       s_waitcnt vmcnt(4); bar     (leaves q3/q4's 4 loads in flight)
// Every region is overwritten only after its last ds_read retired behind a
// barrier; vmcnt(4) guarantees everything the next half-iteration reads landed.
// ---------------------------------------------------------------------------

template <int MH, int NH>
__device__ __forceinline__ void mma_ph(float4v acc[8][4], const short8* aR,
                                       const short8 bR[2][4]) {
  __builtin_amdgcn_s_setprio(1);
#pragma unroll
  for (int fi = 0; fi < 4; ++fi)
#pragma unroll
    for (int fj = 0; fj < 2; ++fj)
#pragma unroll
      for (int s = 0; s < 2; ++s)
        acc[MH * 4 + fi][NH * 2 + fj] = __builtin_amdgcn_mfma_f32_16x16x32_bf16(
            aR[fi * 2 + s], bR[NH][fj * 2 + s], acc[MH * 4 + fi][NH * 2 + fj],
            0, 0, 0);
  __builtin_amdgcn_s_setprio(0);
}

__global__ __launch_bounds__(512, 2) void gemm1_8ph(
    const unsigned short* __restrict__ A, const unsigned short* __restrict__ Bt,
    float* __restrict__ C, long expStride, int ld, int Kc, int zdiv) {
  __shared__ __attribute__((aligned(16))) unsigned short As[2][2][128 * 64];
  __shared__ __attribute__((aligned(16))) unsigned short Bs[2][2][128 * 64];

  const int tid = threadIdx.x;
  const int wv = tid >> 6;
  const int ln = tid & 63;
  const int lrow = ln & 15;
  const int lq = ln >> 4;
  const int wmh = wv >> 2;        // wave M-half (A LDS region)
  const int wnq = wv & 3;         // wave N-quarter
  const int breg = wnq >> 1;      // B LDS region
  const int brow0 = (wnq & 1) * 64;

  // bijective XCD swizzle (grid is 256 in all uses; guard anyway)
  const int nwg = gridDim.x;
  int wg = blockIdx.x;
  if ((nwg & 7) == 0) wg = (wg & 7) * (nwg >> 3) + (wg >> 3);
  const int tile = wg & 15;       // 16 output tiles (4x4 of 256^2)
  const int z = wg >> 4;          // z-chunk: consecutive wg share z -> same XCD
  const int e = z / zdiv;
  const int kc = z % zdiv;
  const int ty = tile >> 2, tx = tile & 3;

  const unsigned short* Ab =
      A + (long)e * expStride + (long)(ty * 256) * ld + (long)kc * Kc;
  const unsigned short* Bb =
      Bt + (long)e * expStride + (long)(tx * 256) * ld + (long)kc * Kc;

  // staging per-lane constants (inverse-swizzled source)
  const int srow = ln >> 3;             // row within 8-row issue
  const int scg = (ln & 7) ^ srow;      // logical k-granule this lane fetches

  auto stageA = [&](int b, int h, int kt) {
#pragma unroll
    for (int i = 0; i < 2; ++i) {
      const unsigned short* g =
          Ab + (long)(h * 128 + wv * 16 + i * 8 + srow) * ld + kt * 64 + scg * 8;
      load_lds_16B(g, (void*)&As[b][h][(wv * 2 + i) * 512]);
    }
  };
  auto stageB = [&](int b, int h, int kt) {
#pragma unroll
    for (int i = 0; i < 2; ++i) {
      const unsigned short* g =
          Bb + (long)(h * 128 + wv * 16 + i * 8 + srow) * ld + kt * 64 + scg * 8;
      load_lds_16B(g, (void*)&Bs[b][h][(wv * 2 + i) * 512]);
    }
  };

  float4v acc[8][4];
  float4v zero4 = {0.0f, 0.0f, 0.0f, 0.0f};
#pragma unroll
  for (int i = 0; i < 8; ++i)
#pragma unroll
    for (int j = 0; j < 4; ++j) acc[i][j] = zero4;

  short8 aR[8];
  short8 bR[2][4];

  auto ldsA = [&](int b, int mh) {
#pragma unroll
    for (int fi = 0; fi < 4; ++fi) {
      const int row = mh * 64 + fi * 16 + lrow;
#pragma unroll
      for (int s = 0; s < 2; ++s) {
        const int cg = (s * 4 + lq) ^ (row & 7);
        aR[fi * 2 + s] = *(const short8*)&As[b][wmh][row * 64 + cg * 8];
      }
    }
  };
  auto ldsB = [&](int b, int nh) {
#pragma unroll
    for (int fj = 0; fj < 2; ++fj) {
      const int row = brow0 + nh * 32 + fj * 16 + lrow;
#pragma unroll
      for (int s = 0; s < 2; ++s) {
        const int cg = (s * 4 + lq) ^ (row & 7);
        bR[nh][fj * 2 + s] = *(const short8*)&Bs[b][breg][row * 64 + cg * 8];
      }
    }
  };

  const int nkt = Kc / 64;  // even in all uses (32 or 16)

  // prologue: buf0 <- K-tile 0 (all 4 halves), buf1 <- K-tile 1 (B halves only;
  // A halves arrive at q1/q2 of iteration 0 per the steady-state rule)
  stageA(0, 0, 0);
  stageA(0, 1, 0);
  stageB(0, 0, 0);
  stageB(0, 1, 0);
  stageB(1, 0, 1);
  stageB(1, 1, 1);
  asm volatile("s_waitcnt vmcnt(4)" ::: "memory");  // buf0 complete
  __builtin_amdgcn_s_barrier();

#define HALF_ITER(B, OB, NN)                                        \
  {                                                                 \
    const int na = ((NN) + 1 < nkt) ? (NN) + 1 : nkt - 1;           \
    const int nb = ((NN) + 2 < nkt) ? (NN) + 2 : nkt - 1;           \
    ldsA(B, 0);                                                     \
    ldsB(B, 0);                                                     \
    stageA(OB, 0, na);                                              \
    __builtin_amdgcn_s_barrier();                                   \
    asm volatile("s_waitcnt lgkmcnt(0)");                           \
    mma_ph<0, 0>(acc, aR, bR);                                      \
    __builtin_amdgcn_s_barrier();                                   \
    ldsB(B, 1);                                                     \
    stageA(OB, 1, na);                                              \
    __builtin_amdgcn_s_barrier();                                   \
    asm volatile("s_waitcnt lgkmcnt(0)");                           \
    mma_ph<0, 1>(acc, aR, bR);                                      \
    __builtin_amdgcn_s_barrier();                                   \
    ldsA(B, 1);                                                     \
    stageB(B, 0, nb);                                               \
    __builtin_amdgcn_s_barrier();                                   \
    asm volatile("s_waitcnt lgkmcnt(0)");                           \
    mma_ph<1, 1>(acc, aR, bR);                                      \
    __builtin_amdgcn_s_barrier();                                   \
    stageB(B, 1, nb);                                               \
    __builtin_amdgcn_s_barrier();                                   \
    mma_ph<1, 0>(acc, aR, bR);                                      \
    asm volatile("s_waitcnt vmcnt(4)" ::: "memory");                \
    __builtin_amdgcn_s_barrier();                                   \
  }

  for (int t = 0; t < nkt; t += 2) {
    HALF_ITER(0, 1, t)
    HALF_ITER(1, 0, t + 1)
  }
#undef HALF_ITER

  asm volatile("s_waitcnt vmcnt(0)" ::: "memory");  // drain clamped tail loads

  // epilogue: C/D layout col=lane&15, row=(lane>>4)*4+reg
  const int crow0 = ty * 256 + wmh * 128 + lq * 4;
  const int ccol0 = tx * 256 + wnq * 64 + lrow;
#pragma unroll
  for (int i = 0; i < 8; ++i)
#pragma unroll
    for (int j = 0; j < 4; ++j)
#pragma unroll
      for (int r = 0; r < 4; ++r)
        atomicAdd(&C[(long)(crow0 + i * 16 + r) * 1024 + ccol0 + j * 16],
                  acc[i][j][r]);
}

// ---------------------------------------------------------------------------
// Old 2-barrier kernel, kept for GEMM2 (x @ W^T, K=1024, 512 blocks).
// C[M][N](fp32) (+)= A(bf16,[m][k],lda) * Bt(bf16,[n][k],ldb)^T
// ---------------------------------------------------------------------------
template <int MI, bool ATOMIC>
__global__ __launch_bounds__(256) void gemm_bf16(
    const unsigned short* __restrict__ A, int lda, long strideA,
    const unsigned short* __restrict__ Bt, int ldb, long strideB,
    float* __restrict__ C, int ldc, int K, int zdiv) {
  constexpr int BM = MI * 32;
  __shared__ __attribute__((aligned(16))) unsigned short As[2 * BM * 32];
  __shared__ __attribute__((aligned(16))) unsigned short Bs[2 * BN * 32];

  const int tid = threadIdx.x;
  const int wv = tid >> 6;
  const int ln = tid & 63;
  const int wm = (wv >> 1) * (MI * 16);
  const int wn = (wv & 1) * 64;
  const int lrow = ln & 15;
  const int lq = ln >> 4;
  const int sfrag = ((lq + (lrow >> 1)) & 3) * 16;  // swizzled frag granule

  const int zb = blockIdx.z / zdiv;
  const int zk = blockIdx.z % zdiv;
  const unsigned short* Ab = A + (long)zb * strideA + (long)zk * K +
                             (long)(blockIdx.y * BM) * lda;
  const unsigned short* Bb = Bt + (long)zb * strideB + (long)zk * K +
                             (long)(blockIdx.x * BN) * ldb;

  float4v zero4 = {0.0f, 0.0f, 0.0f, 0.0f};
  float4v acc[MI][4];
#pragma unroll
  for (int i = 0; i < MI; ++i)
#pragma unroll
    for (int j = 0; j < 4; ++j) acc[i][j] = zero4;

  const int nk = K / 64;
  for (int kt = 0; kt < nk; ++kt) {
    const int k0 = kt * 64;
    __syncthreads();  // WAR: prev iter's frag reads done before restage
#pragma unroll
    for (int s = 0; s < 2; ++s) {
#pragma unroll
      for (int p = 0; p < BM / 64; ++p) {
        int o = p * 256 + wv * 64 + ln;
        int r = o >> 2;
        int gk = ((o & 3) - (r >> 1)) & 3;
        const unsigned short* g = Ab + (long)r * lda + k0 + s * 32 + gk * 8;
        char* lp = (char*)As + s * (BM * 64) + (p * 256 + wv * 64) * 16;
        load_lds_16B(g, lp);
      }
#pragma unroll
      for (int p = 0; p < 2; ++p) {
        int o = p * 256 + wv * 64 + ln;
        int r = o >> 2;
        int gk = ((o & 3) - (r >> 1)) & 3;
        const unsigned short* g = Bb + (long)r * ldb + k0 + s * 32 + gk * 8;
        char* lp = (char*)Bs + s * (BN * 64) + (p * 256 + wv * 64) * 16;
        load_lds_16B(g, lp);
      }
    }
    __syncthreads();  // RAW: staging drained

#pragma unroll
    for (int s = 0; s < 2; ++s) {
      short8 a[MI], b[4];
#pragma unroll
      for (int i = 0; i < MI; ++i)
        a[i] = *(const short8*)((const char*)As + s * (BM * 64) +
                                (wm + i * 16 + lrow) * 64 + sfrag);
#pragma unroll
      for (int j = 0; j < 4; ++j)
        b[j] = *(const short8*)((const char*)Bs + s * (BN * 64) +
                                (wn + j * 16 + lrow) * 64 + sfrag);
#pragma unroll
      for (int i = 0; i < MI; ++i)
#pragma unroll
        for (int j = 0; j < 4; ++j)
          acc[i][j] = __builtin_amdgcn_mfma_f32_16x16x32_bf16(a[i], b[j],
                                                              acc[i][j], 0, 0, 0);
    }
  }

  const int crow0 = blockIdx.y * BM + wm + lq * 4;
  const int ccol0 = blockIdx.x * BN + wn + lrow;
#pragma unroll
  for (int i = 0; i < MI; ++i)
#pragma unroll
    for (int j = 0; j < 4; ++j)
#pragma unroll
      for (int r = 0; r < 4; ++r) {
        int row = crow0 + i * 16 + r;
        int col = ccol0 + j * 16;
        if (ATOMIC)
          atomicAdd(&C[(long)row * ldc + col], acc[i][j][r]);
        else
          C[(long)row * ldc + col] = acc[i][j][r];
      }
}

// elementwise fp32 -> bf16, 8 elems/thread, exact grid (n % 2048 == 0)
__global__ __launch_bounds__(256) void cvt_f32_bf16(
    const float* __restrict__ in, unsigned short* __restrict__ out) {
  long i = ((long)blockIdx.x * 256 + threadIdx.x) * 8;
  float4 v0 = *(const float4*)(in + i);
  float4 v1 = *(const float4*)(in + i + 4);
  uint4v d;
  d.x = pack_bf16(v0.x, v0.y);
  d.y = pack_bf16(v0.z, v0.w);
  d.z = pack_bf16(v1.x, v1.y);
  d.w = pack_bf16(v1.z, v1.w);
  *(uint4v*)(out + i) = d;
}

// in: fp32 [z][R][C] -> out: bf16 [z][C][R]   (64x64 LDS tile transpose + cvt)
__global__ __launch_bounds__(256) void transpose_cvt_kernel(
    const float* __restrict__ in, unsigned short* __restrict__ out,
    int R, int C, long strideBatch) {
  __shared__ float tile[64][65];
  const float* src = in + (long)blockIdx.z * strideBatch;
  unsigned short* dst = out + (long)blockIdx.z * strideBatch;
  const int t = threadIdx.x;
  const int c4 = (t & 15) * 4;
  const int r0 = t >> 4;
  const int by = blockIdx.y * 64;  // R offset
  const int bx = blockIdx.x * 64;  // C offset
#pragma unroll
  for (int p = 0; p < 4; ++p) {
    int r = r0 + p * 16;
    float4 v = *(const float4*)(src + (long)(by + r) * C + bx + c4);
    tile[r][c4 + 0] = v.x;
    tile[r][c4 + 1] = v.y;
    tile[r][c4 + 2] = v.z;
    tile[r][c4 + 3] = v.w;
  }
  __syncthreads();
#pragma unroll
  for (int p = 0; p < 4; ++p) {
    int cc = r0 + p * 16;
    int rr = c4;
    unsigned int d0 = pack_bf16(tile[rr + 0][cc], tile[rr + 1][cc]);
    unsigned int d1 = pack_bf16(tile[rr + 2][cc], tile[rr + 3][cc]);
    uint2 dd;
    dd.x = d0;
    dd.y = d1;
    *(uint2*)(dst + (long)(bx + cc) * R + by + rr) = dd;
  }
}

extern "C" void kernel_launch(void* const* d_in, const int* in_sizes, int n_in,
                              void* d_out, int out_size, void* d_ws, size_t ws_size,
                              hipStream_t stream) {
  const float* x = (const float*)d_in[0];   // [4,1024,1024]
  const float* w1 = (const float*)d_in[1];  // [8,1024,4096]
  const float* w2 = (const float*)d_in[2];  // [8,4096,1024]
  float* out = (float*)d_out;               // [4,1024,1024]

  const int A_ = 4, M_ = 1024, H_ = 1024, E_ = 8, N_ = 4096;
  const long EXP = (long)H_ * N_;  // 4.19M elems per expert

  const size_t need_single =
      (size_t)2 * E_ * EXP * 2 + (size_t)A_ * M_ * H_ * 2 +
      (size_t)H_ * H_ * 4 + (size_t)H_ * H_ * 2;

  if (ws_size >= need_single) {
    // ---------------- single-shot path ----------------
    unsigned short* w2t = (unsigned short*)d_ws;
    unsigned short* w1b = w2t + (long)E_ * EXP;
    unsigned short* xb = w1b + (long)E_ * EXP;
    float* Wacc = (float*)(xb + (long)A_ * M_ * H_);
    unsigned short* Wb = (unsigned short*)(Wacc + (long)H_ * H_);

    cvt_f32_bf16<<<(A_ * M_ * H_) / 2048, 256, 0, stream>>>(x, xb);
    transpose_cvt_kernel<<<dim3(H_ / 64, N_ / 64, E_), 256, 0, stream>>>(
        w2, w2t, N_, H_, EXP);
    cvt_f32_bf16<<<(int)(E_ * EXP / 2048), 256, 0, stream>>>(w1, w1b);
    hipMemsetAsync(Wacc, 0, (size_t)H_ * H_ * 4, stream);

    // GEMM1: 16 tiles x (8 experts x 2 K-chunks of 2048) = 256 blocks
    gemm1_8ph<<<dim3(256), 512, 0, stream>>>(w2t, w1b, Wacc, EXP, N_, N_ / 2, 2);

    cvt_f32_bf16<<<(H_ * H_) / 2048, 256, 0, stream>>>(Wacc, Wb);

    gemm_bf16<2, false><<<dim3(H_ / BN, (A_ * M_) / 64, 1), 256, 0, stream>>>(
        xb, H_, 0, Wb, H_, 0, out, H_, H_, 1);
  } else {
    // ---------------- 2-group fallback (proven at ~82MB) ----------------
    unsigned short* w2t = (unsigned short*)d_ws;
    unsigned short* w1b = w2t + 4 * EXP;
    unsigned short* xb = w1b + 4 * EXP;
    float* Wacc = (float*)(xb + (long)A_ * M_ * H_);
    unsigned short* Wb = (unsigned short*)(Wacc + (long)H_ * H_);

    cvt_f32_bf16<<<(A_ * M_ * H_) / 2048, 256, 0, stream>>>(x, xb);
    hipMemsetAsync(Wacc, 0, (size_t)H_ * H_ * 4, stream);

    for (int g = 0; g < 2; ++g) {
      const float* w2g = w2 + (long)g * 4 * EXP;
      const float* w1g = w1 + (long)g * 4 * EXP;
      transpose_cvt_kernel<<<dim3(H_ / 64, N_ / 64, 4), 256, 0, stream>>>(
          w2g, w2t, N_, H_, EXP);
      cvt_f32_bf16<<<(int)(4 * EXP / 2048), 256, 0, stream>>>(w1g, w1b);
      // 16 tiles x (4 experts x 4 K-chunks of 1024) = 256 blocks
      gemm1_8ph<<<dim3(256), 512, 0, stream>>>(w2t, w1b, Wacc, EXP, N_, N_ / 4, 4);
    }

    cvt_f32_bf16<<<(H_ * H_) / 2048, 256, 0, stream>>>(Wacc, Wb);
    gemm_bf16<2, false><<<dim3(H_ / BN, (A_ * M_) / 64, 1), 256, 0, stream>>>(
        xb, H_, 0, Wb, H_, 0, out, H_, H_, 1);
  }
}

// Round 4
// 402.589 us; speedup vs baseline: 1.1675x; 1.0613x over previous
//
#include <hip/hip_runtime.h>
#include <hip/hip_bf16.h>
#include <stdint.h>

// out = x @ (sum_e w1[e] @ w2[e])   -- reassociated two-einsum.
// GEMM1: 256x256-tile 8-phase schedule (T2+T3+T4+T5), split-K over
//   z = expert * zdiv + kchunk.  A=w2t, Bt=w1b (both bf16 [e][row][k], ld=4096).
// R4: fixes R2/R3's LDS race. Each wave reads its A region As[B][wmh] in BOTH
//   q1 (rows 0-63) and q3 (rows 64-127); R2 staged As[B][0] at q2 -> tile-n+2
//   data could land before q3's reads of tile n (absmax 8.45). Now every stage
//   is issued only in the phase after the region's LAST ds_read drained behind
//   a barrier: B regions (last read q2) staged q3; A regions (last read q3)
//   staged q4. Still 2 K-tiles ahead into the CURRENT buffer -> cover ~5-6
//   phases; end-of-tile s_waitcnt vmcnt(8) = prev tile's 8 loads landed,
//   this tile's 8 in flight.
// Epilogue: per-z partial slices + fused reduce16_cvt (no atomics) when ws
//   allows; atomic path and 2-group fallback kept.
// GEMM2: old 2-barrier 64x128 kernel (small, revisit later).

#define BN 128

typedef __attribute__((ext_vector_type(8))) short short8;
typedef __attribute__((ext_vector_type(4))) float float4v;
typedef __attribute__((ext_vector_type(4))) unsigned int uint4v;

__device__ __forceinline__ unsigned int rne_hi(unsigned int u) {
  return u + 0x7fffu + ((u >> 16) & 1u);
}

__device__ __forceinline__ unsigned int pack_bf16(float lo, float hi) {
  unsigned int ulo = rne_hi(__float_as_uint(lo));
  unsigned int uhi = rne_hi(__float_as_uint(hi));
  return __builtin_amdgcn_perm(uhi, ulo, 0x07060302u);
}

__device__ __forceinline__ void load_lds_16B(const void* g, void* lds) {
  __builtin_amdgcn_global_load_lds(
      (__attribute__((address_space(1))) void*)(uintptr_t)g,
      (__attribute__((address_space(3))) void*)(unsigned int)(uintptr_t)lds,
      16, 0, 0);
}

// ---------------------------------------------------------------------------
// GEMM1 phase schedule per K-tile n in buffer b:
//   q1: ds A(rows 0-63)x8 + B(rows 0-31)x4 ; bar; lgkm0; MFMA M0N0; bar
//   q2: ds B(rows 32-63)x4                 ; bar; lgkm0; MFMA M0N1; bar
//   q3: ds A(rows 64-127)x8; stage b.B0,b.B1 <- n+2; bar; lgkm0; MFMA M1N1; bar
//   q4: stage b.A0,b.A1 <- n+2             ; bar;        MFMA M1N0;
//       s_waitcnt vmcnt(8); bar
// Region-safety (per PHYSICAL region, all readers):
//   Bs[b][*]: read q1+q2 (all waves' breg) -> staged q3 (after q2 lgkm0+bar).
//   As[b][*]: read q1+q3 (all waves' wmh)  -> staged q4 (after q3 lgkm0+bar).
// Cross-wave: stage issued only after a barrier that all waves reach having
// drained (lgkmcnt(0)) every read of that region.
// vmcnt(8) before closing bar: this half-iter issued exactly 8 loads (4 B @q3,
// 4 A @q4); 8 outstanding allowed -> all prior half-iter loads landed -> next
// half-iter's buffer is complete when any wave crosses the bar.
// Tail: stage target clamped to nkt-1 (rewrites identical bytes or writes a
// never-read buffer); final vmcnt(0) drains.
// ---------------------------------------------------------------------------

template <int MH, int NH>
__device__ __forceinline__ void mma_ph(float4v acc[8][4], const short8* aR,
                                       const short8 bR[2][4]) {
  __builtin_amdgcn_s_setprio(1);
#pragma unroll
  for (int fi = 0; fi < 4; ++fi)
#pragma unroll
    for (int fj = 0; fj < 2; ++fj)
#pragma unroll
      for (int s = 0; s < 2; ++s)
        acc[MH * 4 + fi][NH * 2 + fj] = __builtin_amdgcn_mfma_f32_16x16x32_bf16(
            aR[fi * 2 + s], bR[NH][fj * 2 + s], acc[MH * 4 + fi][NH * 2 + fj],
            0, 0, 0);
  __builtin_amdgcn_s_setprio(0);
}

template <bool ATOMIC>
__global__ __launch_bounds__(512, 2) void gemm1_8ph(
    const unsigned short* __restrict__ A, const unsigned short* __restrict__ Bt,
    float* __restrict__ C, long expStride, int ld, int Kc, int zdiv) {
  __shared__ __attribute__((aligned(16))) unsigned short As[2][2][128 * 64];
  __shared__ __attribute__((aligned(16))) unsigned short Bs[2][2][128 * 64];

  const int tid = threadIdx.x;
  const int wv = tid >> 6;
  const int ln = tid & 63;
  const int lrow = ln & 15;
  const int lq = ln >> 4;
  const int wmh = wv >> 2;        // wave M-half (A LDS region)
  const int wnq = wv & 3;         // wave N-quarter
  const int breg = wnq >> 1;      // B LDS region
  const int brow0 = (wnq & 1) * 64;

  // bijective XCD swizzle (grid is 256 in all uses; guard anyway)
  const int nwg = gridDim.x;
  int wg = blockIdx.x;
  if ((nwg & 7) == 0) wg = (wg & 7) * (nwg >> 3) + (wg >> 3);
  const int tile = wg & 15;       // 16 output tiles (4x4 of 256^2)
  const int z = wg >> 4;          // z-chunk: consecutive wg share z -> same XCD
  const int e = z / zdiv;
  const int kc = z % zdiv;
  const int ty = tile >> 2, tx = tile & 3;

  const unsigned short* Ab =
      A + (long)e * expStride + (long)(ty * 256) * ld + (long)kc * Kc;
  const unsigned short* Bb =
      Bt + (long)e * expStride + (long)(tx * 256) * ld + (long)kc * Kc;

  // staging per-lane constants (inverse-swizzled source)
  const int srow = ln >> 3;             // row within 8-row issue
  const int scg = (ln & 7) ^ srow;      // logical k-granule this lane fetches

  auto stageA = [&](int b, int h, int kt) {
#pragma unroll
    for (int i = 0; i < 2; ++i) {
      const unsigned short* g =
          Ab + (long)(h * 128 + wv * 16 + i * 8 + srow) * ld + kt * 64 + scg * 8;
      load_lds_16B(g, (void*)&As[b][h][(wv * 2 + i) * 512]);
    }
  };
  auto stageB = [&](int b, int h, int kt) {
#pragma unroll
    for (int i = 0; i < 2; ++i) {
      const unsigned short* g =
          Bb + (long)(h * 128 + wv * 16 + i * 8 + srow) * ld + kt * 64 + scg * 8;
      load_lds_16B(g, (void*)&Bs[b][h][(wv * 2 + i) * 512]);
    }
  };

  float4v acc[8][4];
  float4v zero4 = {0.0f, 0.0f, 0.0f, 0.0f};
#pragma unroll
  for (int i = 0; i < 8; ++i)
#pragma unroll
    for (int j = 0; j < 4; ++j) acc[i][j] = zero4;

  short8 aR[8];
  short8 bR[2][4];

  auto ldsA = [&](int b, int mh) {
#pragma unroll
    for (int fi = 0; fi < 4; ++fi) {
      const int row = mh * 64 + fi * 16 + lrow;
#pragma unroll
      for (int s = 0; s < 2; ++s) {
        const int cg = (s * 4 + lq) ^ (row & 7);
        aR[fi * 2 + s] = *(const short8*)&As[b][wmh][row * 64 + cg * 8];
      }
    }
  };
  auto ldsB = [&](int b, int nh) {
#pragma unroll
    for (int fj = 0; fj < 2; ++fj) {
      const int row = brow0 + nh * 32 + fj * 16 + lrow;
#pragma unroll
      for (int s = 0; s < 2; ++s) {
        const int cg = (s * 4 + lq) ^ (row & 7);
        bR[nh][fj * 2 + s] = *(const short8*)&Bs[b][breg][row * 64 + cg * 8];
      }
    }
  };

  const int nkt = Kc / 64;  // even in all uses (32 or 16)

  // prologue: buf0 <- K-tile 0, buf1 <- K-tile 1 (full tiles, 8 loads each)
  stageA(0, 0, 0);
  stageA(0, 1, 0);
  stageB(0, 0, 0);
  stageB(0, 1, 0);
  stageA(1, 0, 1);
  stageA(1, 1, 1);
  stageB(1, 0, 1);
  stageB(1, 1, 1);
  asm volatile("s_waitcnt vmcnt(8)" ::: "memory");  // buf0 complete
  __builtin_amdgcn_s_barrier();

#define HALF_ITER(B, NN)                                            \
  {                                                                 \
    const int n2 = ((NN) + 2 < nkt) ? (NN) + 2 : nkt - 1;           \
    ldsA(B, 0);                                                     \
    ldsB(B, 0);                                                     \
    __builtin_amdgcn_s_barrier();                                   \
    asm volatile("s_waitcnt lgkmcnt(0)");                           \
    mma_ph<0, 0>(acc, aR, bR);                                      \
    __builtin_amdgcn_s_barrier();                                   \
    ldsB(B, 1);                                                     \
    __builtin_amdgcn_s_barrier();                                   \
    asm volatile("s_waitcnt lgkmcnt(0)");                           \
    mma_ph<0, 1>(acc, aR, bR);                                      \
    __builtin_amdgcn_s_barrier();                                   \
    ldsA(B, 1);                                                     \
    stageB(B, 0, n2);                                               \
    stageB(B, 1, n2);                                               \
    __builtin_amdgcn_s_barrier();                                   \
    asm volatile("s_waitcnt lgkmcnt(0)");                           \
    mma_ph<1, 1>(acc, aR, bR);                                      \
    __builtin_amdgcn_s_barrier();                                   \
    stageA(B, 0, n2);                                               \
    stageA(B, 1, n2);                                               \
    __builtin_amdgcn_s_barrier();                                   \
    mma_ph<1, 0>(acc, aR, bR);                                      \
    asm volatile("s_waitcnt vmcnt(8)" ::: "memory");                \
    __builtin_amdgcn_s_barrier();                                   \
  }

  for (int t = 0; t < nkt; t += 2) {
    HALF_ITER(0, t)
    HALF_ITER(1, t + 1)
  }
#undef HALF_ITER

  asm volatile("s_waitcnt vmcnt(0)" ::: "memory");  // drain clamped tail loads

  // epilogue: C/D layout col=lane&15, row=(lane>>4)*4+reg
  float* Cz = ATOMIC ? C : C + (long)z * (1024L * 1024L);
  const int crow0 = ty * 256 + wmh * 128 + lq * 4;
  const int ccol0 = tx * 256 + wnq * 64 + lrow;
#pragma unroll
  for (int i = 0; i < 8; ++i)
#pragma unroll
    for (int j = 0; j < 4; ++j)
#pragma unroll
      for (int r = 0; r < 4; ++r) {
        const long idx = (long)(crow0 + i * 16 + r) * 1024 + ccol0 + j * 16;
        if (ATOMIC)
          atomicAdd(&Cz[idx], acc[i][j][r]);
        else
          Cz[idx] = acc[i][j][r];
      }
}

// Wb[i] = bf16( sum_{z<16} Wpart[z][i] )  -- fused split-K reduce + cvt
__global__ __launch_bounds__(256) void reduce16_cvt(
    const float* __restrict__ in, unsigned short* __restrict__ out) {
  const long i = ((long)blockIdx.x * 256 + threadIdx.x) * 4;
  float4 s = *(const float4*)(in + i);
#pragma unroll
  for (int zz = 1; zz < 16; ++zz) {
    float4 v = *(const float4*)(in + (long)zz * (1024L * 1024L) + i);
    s.x += v.x;
    s.y += v.y;
    s.z += v.z;
    s.w += v.w;
  }
  uint2 d;
  d.x = pack_bf16(s.x, s.y);
  d.y = pack_bf16(s.z, s.w);
  *(uint2*)(out + i) = d;
}

// ---------------------------------------------------------------------------
// Old 2-barrier kernel, kept for GEMM2 (x @ W^T, K=1024, 512 blocks).
// C[M][N](fp32) (+)= A(bf16,[m][k],lda) * Bt(bf16,[n][k],ldb)^T
// ---------------------------------------------------------------------------
template <int MI, bool ATOMIC>
__global__ __launch_bounds__(256) void gemm_bf16(
    const unsigned short* __restrict__ A, int lda, long strideA,
    const unsigned short* __restrict__ Bt, int ldb, long strideB,
    float* __restrict__ C, int ldc, int K, int zdiv) {
  constexpr int BM = MI * 32;
  __shared__ __attribute__((aligned(16))) unsigned short As[2 * BM * 32];
  __shared__ __attribute__((aligned(16))) unsigned short Bs[2 * BN * 32];

  const int tid = threadIdx.x;
  const int wv = tid >> 6;
  const int ln = tid & 63;
  const int wm = (wv >> 1) * (MI * 16);
  const int wn = (wv & 1) * 64;
  const int lrow = ln & 15;
  const int lq = ln >> 4;
  const int sfrag = ((lq + (lrow >> 1)) & 3) * 16;  // swizzled frag granule

  const int zb = blockIdx.z / zdiv;
  const int zk = blockIdx.z % zdiv;
  const unsigned short* Ab = A + (long)zb * strideA + (long)zk * K +
                             (long)(blockIdx.y * BM) * lda;
  const unsigned short* Bb = Bt + (long)zb * strideB + (long)zk * K +
                             (long)(blockIdx.x * BN) * ldb;

  float4v zero4 = {0.0f, 0.0f, 0.0f, 0.0f};
  float4v acc[MI][4];
#pragma unroll
  for (int i = 0; i < MI; ++i)
#pragma unroll
    for (int j = 0; j < 4; ++j) acc[i][j] = zero4;

  const int nk = K / 64;
  for (int kt = 0; kt < nk; ++kt) {
    const int k0 = kt * 64;
    __syncthreads();  // WAR: prev iter's frag reads done before restage
#pragma unroll
    for (int s = 0; s < 2; ++s) {
#pragma unroll
      for (int p = 0; p < BM / 64; ++p) {
        int o = p * 256 + wv * 64 + ln;
        int r = o >> 2;
        int gk = ((o & 3) - (r >> 1)) & 3;
        const unsigned short* g = Ab + (long)r * lda + k0 + s * 32 + gk * 8;
        char* lp = (char*)As + s * (BM * 64) + (p * 256 + wv * 64) * 16;
        load_lds_16B(g, lp);
      }
#pragma unroll
      for (int p = 0; p < 2; ++p) {
        int o = p * 256 + wv * 64 + ln;
        int r = o >> 2;
        int gk = ((o & 3) - (r >> 1)) & 3;
        const unsigned short* g = Bb + (long)r * ldb + k0 + s * 32 + gk * 8;
        char* lp = (char*)Bs + s * (BN * 64) + (p * 256 + wv * 64) * 16;
        load_lds_16B(g, lp);
      }
    }
    __syncthreads();  // RAW: staging drained

#pragma unroll
    for (int s = 0; s < 2; ++s) {
      short8 a[MI], b[4];
#pragma unroll
      for (int i = 0; i < MI; ++i)
        a[i] = *(const short8*)((const char*)As + s * (BM * 64) +
                                (wm + i * 16 + lrow) * 64 + sfrag);
#pragma unroll
      for (int j = 0; j < 4; ++j)
        b[j] = *(const short8*)((const char*)Bs + s * (BN * 64) +
                                (wn + j * 16 + lrow) * 64 + sfrag);
#pragma unroll
      for (int i = 0; i < MI; ++i)
#pragma unroll
        for (int j = 0; j < 4; ++j)
          acc[i][j] = __builtin_amdgcn_mfma_f32_16x16x32_bf16(a[i], b[j],
                                                              acc[i][j], 0, 0, 0);
    }
  }

  const int crow0 = blockIdx.y * BM + wm + lq * 4;
  const int ccol0 = blockIdx.x * BN + wn + lrow;
#pragma unroll
  for (int i = 0; i < MI; ++i)
#pragma unroll
    for (int j = 0; j < 4; ++j)
#pragma unroll
      for (int r = 0; r < 4; ++r) {
        int row = crow0 + i * 16 + r;
        int col = ccol0 + j * 16;
        if (ATOMIC)
          atomicAdd(&C[(long)row * ldc + col], acc[i][j][r]);
        else
          C[(long)row * ldc + col] = acc[i][j][r];
      }
}

// elementwise fp32 -> bf16, 8 elems/thread, exact grid (n % 2048 == 0)
__global__ __launch_bounds__(256) void cvt_f32_bf16(
    const float* __restrict__ in, unsigned short* __restrict__ out) {
  long i = ((long)blockIdx.x * 256 + threadIdx.x) * 8;
  float4 v0 = *(const float4*)(in + i);
  float4 v1 = *(const float4*)(in + i + 4);
  uint4v d;
  d.x = pack_bf16(v0.x, v0.y);
  d.y = pack_bf16(v0.z, v0.w);
  d.z = pack_bf16(v1.x, v1.y);
  d.w = pack_bf16(v1.z, v1.w);
  *(uint4v*)(out + i) = d;
}

// in: fp32 [z][R][C] -> out: bf16 [z][C][R]   (64x64 LDS tile transpose + cvt)
__global__ __launch_bounds__(256) void transpose_cvt_kernel(
    const float* __restrict__ in, unsigned short* __restrict__ out,
    int R, int C, long strideBatch) {
  __shared__ float tile[64][65];
  const float* src = in + (long)blockIdx.z * strideBatch;
  unsigned short* dst = out + (long)blockIdx.z * strideBatch;
  const int t = threadIdx.x;
  const int c4 = (t & 15) * 4;
  const int r0 = t >> 4;
  const int by = blockIdx.y * 64;  // R offset
  const int bx = blockIdx.x * 64;  // C offset
#pragma unroll
  for (int p = 0; p < 4; ++p) {
    int r = r0 + p * 16;
    float4 v = *(const float4*)(src + (long)(by + r) * C + bx + c4);
    tile[r][c4 + 0] = v.x;
    tile[r][c4 + 1] = v.y;
    tile[r][c4 + 2] = v.z;
    tile[r][c4 + 3] = v.w;
  }
  __syncthreads();
#pragma unroll
  for (int p = 0; p < 4; ++p) {
    int cc = r0 + p * 16;
    int rr = c4;
    unsigned int d0 = pack_bf16(tile[rr + 0][cc], tile[rr + 1][cc]);
    unsigned int d1 = pack_bf16(tile[rr + 2][cc], tile[rr + 3][cc]);
    uint2 dd;
    dd.x = d0;
    dd.y = d1;
    *(uint2*)(dst + (long)(bx + cc) * R + by + rr) = dd;
  }
}

extern "C" void kernel_launch(void* const* d_in, const int* in_sizes, int n_in,
                              void* d_out, int out_size, void* d_ws, size_t ws_size,
                              hipStream_t stream) {
  const float* x = (const float*)d_in[0];   // [4,1024,1024]
  const float* w1 = (const float*)d_in[1];  // [8,1024,4096]
  const float* w2 = (const float*)d_in[2];  // [8,4096,1024]
  float* out = (float*)d_out;               // [4,1024,1024]

  const int A_ = 4, M_ = 1024, H_ = 1024, E_ = 8, N_ = 4096;
  const long EXP = (long)H_ * N_;  // 4.19M elems per expert

  // ws tiers
  const size_t base = (size_t)2 * E_ * EXP * 2 + (size_t)A_ * M_ * H_ * 2;
  const size_t need_part = base + 16ull * H_ * H_ * 4 + (size_t)H_ * H_ * 2;
  const size_t need_single = base + (size_t)H_ * H_ * 4 + (size_t)H_ * H_ * 2;

  if (ws_size >= need_part) {
    // ---------------- partial-store path (no atomics) ----------------
    unsigned short* w2t = (unsigned short*)d_ws;
    unsigned short* w1b = w2t + (long)E_ * EXP;
    unsigned short* xb = w1b + (long)E_ * EXP;
    float* Wpart = (float*)(xb + (long)A_ * M_ * H_);  // [16][1024][1024]
    unsigned short* Wb = (unsigned short*)(Wpart + 16L * H_ * H_);

    cvt_f32_bf16<<<(A_ * M_ * H_) / 2048, 256, 0, stream>>>(x, xb);
    transpose_cvt_kernel<<<dim3(H_ / 64, N_ / 64, E_), 256, 0, stream>>>(
        w2, w2t, N_, H_, EXP);
    cvt_f32_bf16<<<(int)(E_ * EXP / 2048), 256, 0, stream>>>(w1, w1b);

    // GEMM1: 16 tiles x (8 experts x 2 K-chunks of 2048) = 256 blocks
    gemm1_8ph<false><<<dim3(256), 512, 0, stream>>>(w2t, w1b, Wpart, EXP, N_,
                                                    N_ / 2, 2);
    reduce16_cvt<<<(H_ * H_) / 1024, 256, 0, stream>>>(Wpart, Wb);

    gemm_bf16<2, false><<<dim3(H_ / BN, (A_ * M_) / 64, 1), 256, 0, stream>>>(
        xb, H_, 0, Wb, H_, 0, out, H_, H_, 1);
  } else if (ws_size >= need_single) {
    // ---------------- atomic single-shot path ----------------
    unsigned short* w2t = (unsigned short*)d_ws;
    unsigned short* w1b = w2t + (long)E_ * EXP;
    unsigned short* xb = w1b + (long)E_ * EXP;
    float* Wacc = (float*)(xb + (long)A_ * M_ * H_);
    unsigned short* Wb = (unsigned short*)(Wacc + (long)H_ * H_);

    cvt_f32_bf16<<<(A_ * M_ * H_) / 2048, 256, 0, stream>>>(x, xb);
    transpose_cvt_kernel<<<dim3(H_ / 64, N_ / 64, E_), 256, 0, stream>>>(
        w2, w2t, N_, H_, EXP);
    cvt_f32_bf16<<<(int)(E_ * EXP / 2048), 256, 0, stream>>>(w1, w1b);
    hipMemsetAsync(Wacc, 0, (size_t)H_ * H_ * 4, stream);

    gemm1_8ph<true><<<dim3(256), 512, 0, stream>>>(w2t, w1b, Wacc, EXP, N_,
                                                   N_ / 2, 2);
    cvt_f32_bf16<<<(H_ * H_) / 2048, 256, 0, stream>>>(Wacc, Wb);

    gemm_bf16<2, false><<<dim3(H_ / BN, (A_ * M_) / 64, 1), 256, 0, stream>>>(
        xb, H_, 0, Wb, H_, 0, out, H_, H_, 1);
  } else {
    // ---------------- 2-group fallback (proven at ~82MB) ----------------
    unsigned short* w2t = (unsigned short*)d_ws;
    unsigned short* w1b = w2t + 4 * EXP;
    unsigned short* xb = w1b + 4 * EXP;
    float* Wacc = (float*)(xb + (long)A_ * M_ * H_);
    unsigned short* Wb = (unsigned short*)(Wacc + (long)H_ * H_);

    cvt_f32_bf16<<<(A_ * M_ * H_) / 2048, 256, 0, stream>>>(x, xb);
    hipMemsetAsync(Wacc, 0, (size_t)H_ * H_ * 4, stream);

    for (int g = 0; g < 2; ++g) {
      const float* w2g = w2 + (long)g * 4 * EXP;
      const float* w1g = w1 + (long)g * 4 * EXP;
      transpose_cvt_kernel<<<dim3(H_ / 64, N_ / 64, 4), 256, 0, stream>>>(
          w2g, w2t, N_, H_, EXP);
      cvt_f32_bf16<<<(int)(4 * EXP / 2048), 256, 0, stream>>>(w1g, w1b);
      // 16 tiles x (4 experts x 4 K-chunks of 1024) = 256 blocks
      gemm1_8ph<true><<<dim3(256), 512, 0, stream>>>(w2t, w1b, Wacc, EXP, N_,
                                                     N_ / 4, 4);
    }

    cvt_f32_bf16<<<(H_ * H_) / 2048, 256, 0, stream>>>(Wacc, Wb);
    gemm_bf16<2, false><<<dim3(H_ / BN, (A_ * M_) / 64, 1), 256, 0, stream>>>(
        xb, H_, 0, Wb, H_, 0, out, H_, H_, 1);
  }
}